// Round 11
// baseline (85.353 us; speedup 1.0000x reference)
//
#include <hip/hip_runtime.h>

#define BATCH  8
#define NPTS   16384
#define LVOX   605     // 11*11*5 = 121 xy-columns * 5 z
#define ABINS  8
#define CH     23
#define NCOL   121
#define SPTS   64      // points per 128-lane group
#define GRPS   4       // groups per block (512 threads)
#define BPTS   (SPTS * GRPS)          // 256 points per feature block
#define FEAT_BLOCKS (BATCH * (NPTS / BPTS))   // 8*64 = 512
#define ROT_CH    4
#define ROT_CHPTS (NPTS / ROT_CH)             // 4096
#define ROT_BLOCKS (ABINS * BATCH * ROT_CH)   // 256

#define ROT_WS_INTS (ABINS * BATCH * LVOX)    // 38720 ints  = 154880 B
#define FEAT_WS_ULL (BATCH * LVOX * 4)        // 19360 ull   = 154880 B
#define WS_ULL_TOTAL (ROT_WS_INTS / 2 + FEAT_WS_ULL)   // 38720 ull

#define MASK8  0x0F0F0F0F0F0F0F0Full
#define MASK16 0x00FF00FF00FF00FFull

// ---------------------------------------------------------------------------
// Workspace zeroing (310 KB).  Runs AFTER the probe kernels, so probe garbage
// in ws is wiped before the real accumulation.
// ---------------------------------------------------------------------------
__global__ __launch_bounds__(256) void zero_kernel(unsigned long long* __restrict__ ws) {
    const int i = blockIdx.x * 256 + threadIdx.x;
    if (i < WS_ULL_TOTAL) ws[i] = 0ull;
}

// ---------------------------------------------------------------------------
// Templated main kernel.  V=0: real R10 kernel.  V=1: probe, sqrt replaced by
// mul (isolates trans-pipe cost).  V=2: probe, 64-bit nibble accumulate
// replaced by plain int add (isolates accumulate cost).  Probes write to a
// dummy ws region (zeroed afterwards) and skip the reduce epilogue.
// ---------------------------------------------------------------------------
template<int V>
__global__ __launch_bounds__(512, 4) void main_t(const float* __restrict__ pcd,
                                                 int* __restrict__ rot_hist,
                                                 unsigned long long* __restrict__ feat_hist) {
    __shared__ unsigned long long lds[5][2][GRPS][129];   // 41.3 KB reduce buffer
    __shared__ float lds_pts[BPTS][4];                    // 4 KB staged points
    const int bid = blockIdx.x;
    const int tid = threadIdx.x;

    if (bid < FEAT_BLOCKS) {
        const int b     = bid >> 6;      // /64
        const int outer = bid & 63;
        const int g4 = __builtin_amdgcn_readfirstlane(tid >> 7);
        const int li = tid & 127;
        const int cc = (li < NCOL) ? li : (NCOL - 1);
        const float lx = -5.0f + (float)(cc / 11);
        const float ly = -5.0f + (float)(cc % 11);

        // ---- stage 256 points (3 KB) into LDS, padded to float4 ----
        {
            const float* __restrict__ src = pcd + ((size_t)b * NPTS + outer * BPTS) * 3;
            for (int i = tid; i < BPTS * 3; i += 512) {
                lds_pts[i / 3][i % 3] = src[i];
            }
        }
        __syncthreads();

        const int pbase = g4 * SPTS;

        unsigned long long be0 = 0, bo0 = 0, be1 = 0, bo1 = 0, be2 = 0, bo2 = 0,
                           be3 = 0, bo3 = 0, be4 = 0, bo4 = 0;
        int isum = 0;

        // per-z chain; V=1 swaps sqrt for mul (bin<=12, shift ok);
        // V=2 swaps the 64-bit nibble accumulate for a plain int add.
#define ZCH(NX, ZC)                                                             \
        {                                                                       \
            const float dz = dz0 - ZC;                                          \
            const float d2z = fmaf(dz, dz, rxy2);                               \
            float d;                                                            \
            if constexpr (V == 1) d = d2z * 0.0625f;                            \
            else                  d = __builtin_amdgcn_sqrtf(d2z);              \
            const int k = (int)d;                                               \
            if constexpr (V == 2) isum += k;                                    \
            else                  NX += 1ull << (k << 2);                       \
        }

#define PT(J)                                                                   \
        {                                                                       \
            const float4 P = *(const float4*)&lds_pts[pbase + (J)][0];          \
            const float dx = P.x - lx, dy = P.y - ly;                           \
            const float rxy2 = fmaf(dy, dy, dx * dx);                           \
            const float dz0 = P.z + 2.0f;                                       \
            ZCH(n0, 0.0f) ZCH(n1, 1.0f) ZCH(n2, 2.0f) ZCH(n3, 3.0f) ZCH(n4, 4.0f) \
        }

#define MERGE()                                                                 \
        if constexpr (V != 2) {                                                 \
            be0 += n0 & MASK8; bo0 += (n0 >> 4) & MASK8;                        \
            be1 += n1 & MASK8; bo1 += (n1 >> 4) & MASK8;                        \
            be2 += n2 & MASK8; bo2 += (n2 >> 4) & MASK8;                        \
            be3 += n3 & MASK8; bo3 += (n3 >> 4) & MASK8;                        \
            be4 += n4 & MASK8; bo4 += (n4 >> 4) & MASK8;                        \
        }

#pragma unroll
        for (int grp = 0; grp < 4; ++grp) {       // fully unrolled: 4 x 15 pts
            const int base = grp * 15;
            unsigned long long n0 = 0, n1 = 0, n2 = 0, n3 = 0, n4 = 0;
#pragma unroll
            for (int j = 0; j < 15; ++j) PT(base + j)
            MERGE()
        }
        {                                          // tail: points 60..63
            unsigned long long n0 = 0, n1 = 0, n2 = 0, n3 = 0, n4 = 0;
#pragma unroll
            for (int j = 60; j < 64; ++j) PT(j)
            MERGE()
        }
#undef PT
#undef ZCH
#undef MERGE

        if constexpr (V != 0) {
            // probe epilogue: keep results live, dump to dummy ws region
            unsigned long long t = (V == 2)
                ? (unsigned long long)isum
                : (be0 + bo0 + be1 + bo1 + be2 + bo2 + be3 + bo3 + be4 + bo4);
            atomicAdd(&feat_hist[tid & 1023], t);
            return;
        }

        lds[0][0][g4][li] = be0;  lds[0][1][g4][li] = bo0;
        lds[1][0][g4][li] = be1;  lds[1][1][g4][li] = bo1;
        lds[2][0][g4][li] = be2;  lds[2][1][g4][li] = bo2;
        lds[3][0][g4][li] = be3;  lds[3][1][g4][li] = bo3;
        lds[4][0][g4][li] = be4;  lds[4][1][g4][li] = bo4;
        __syncthreads();

        // combine 4 groups (byte domain -> 16-bit domain), 2 atomics per item
        for (int item = tid; item < LVOX * 2; item += 512) {
            const int loc = item >> 1;
            const int eo  = item & 1;
            const int col = loc / 5;
            const int z   = loc % 5;
            unsigned long long slo = 0, shi = 0;
#pragma unroll
            for (int g = 0; g < GRPS; ++g) {
                const unsigned long long v = lds[z][eo][g][col];
                slo += v & MASK16;
                shi += (v >> 8) & MASK16;
            }
            unsigned long long* __restrict__ dst =
                feat_hist + ((size_t)b * LVOX + loc) * 4 + eo * 2;
            atomicAdd(&dst[0], slo);
            atomicAdd(&dst[1], shi);
        }
    } else {
        // ------------------ rotation-voxel histogram ------------------
        const int rb    = bid - FEAT_BLOCKS;
        const int ab    = rb & 63;        // a*8 + b
        const int chunk = rb >> 6;        // 0..3
        const int a     = ab >> 3;
        const int b     = ab & 7;

        int* h = (int*)&lds[0][0][0][0];
        for (int i = tid; i < LVOX; i += 512) h[i] = 0;
        __syncthreads();

        const float C[8] = { -4.3711388e-08f, 0.3826834323650898f, 0.7071067811865476f,
                             0.9238795325112867f, 1.0f, 0.9238795325112867f,
                             0.7071067811865476f, 0.3826834323650898f };
        const float S[8] = { -1.0f, -0.9238795325112867f, -0.7071067811865476f,
                             -0.3826834323650898f, 0.0f, 0.3826834323650898f,
                             0.7071067811865476f, 0.9238795325112867f };
        const float c = C[a];
        const float s = S[a];

        const float* __restrict__ p =
            pcd + ((size_t)b * NPTS + (size_t)chunk * ROT_CHPTS) * 3;

        for (int n = tid; n < ROT_CHPTS; n += 512) {
            const float x = p[n * 3 + 0];
            const float y = p[n * 3 + 1];
            const float z = p[n * 3 + 2];
            const float rx = x * c - y * s + 5.5f;
            const float ry = x * s + y * c + 5.5f;
            const float rz = z + 2.5f;
            const int icx = (int)floorf(rx);
            const int icy = (int)floorf(ry);
            const int icz = (int)floorf(rz);
            const int flat = icz + icy * 5 + icx * 55;
            if (flat >= 0 && flat < LVOX) atomicAdd(&h[flat], 1);
        }
        __syncthreads();

        int* __restrict__ dst = rot_hist + (size_t)ab * LVOX;
        for (int i = tid; i < LVOX; i += 512) {
            const int v = h[i];
            if (v) atomicAdd(&dst[i], v);
        }
    }
}

// ---------------------------------------------------------------------------
// Finalize.  16-lane groups; bin q lives in ull word w = ((q&1)<<1)|((q>>1)&1),
// 16-bit slot q>>2.  Prefix-scan, write features + rot channels.
// ---------------------------------------------------------------------------
__global__ __launch_bounds__(256) void write_kernel(const int* __restrict__ rot_hist,
                                                    const unsigned* __restrict__ feat_hist32,
                                                    float* __restrict__ out) {
    const int gt    = blockIdx.x * 256 + threadIdx.x;
    const int group = gt >> 4;                 // (b,l)
    const int q     = gt & 15;
    if (group >= BATCH * LVOX) return;
    const int b = group / LVOX;
    const int l = group % LVOX;

    const int w    = ((q & 1) << 1) | ((q >> 1) & 1);
    const int slot = q >> 2;
    const unsigned word = feat_hist32[(size_t)group * 8 + w * 2 + (slot >> 1)];
    int v = (int)((word >> (16 * (slot & 1))) & 0xFFFFu);
#pragma unroll
    for (int off = 1; off < 16; off <<= 1) {
        const int t = __shfl_up(v, off, 16);
        if (q >= off) v += t;
    }
    const float inv_n = 1.0f / (float)NPTS;
    float* __restrict__ o = out + (size_t)group * CH;
    if (q < 15) o[q] = (float)v * inv_n;
    if (q < 8) {
        const int r = rot_hist[((size_t)q * BATCH + b) * LVOX + l];
        o[15 + q] = (float)r * inv_n;
    }
}

extern "C" void kernel_launch(void* const* d_in, const int* in_sizes, int n_in,
                              void* d_out, int out_size, void* d_ws, size_t ws_size,
                              hipStream_t stream) {
    const float* pcd = (const float*)d_in[0];
    float* out = (float*)d_out;
    int* rot_hist = (int*)d_ws;
    unsigned long long* feat_hist =
        (unsigned long long*)((char*)d_ws + (size_t)ROT_WS_INTS * sizeof(int));

    // dummy targets for probes: the rot region (int view) + its ull view.
    // Probes run FIRST; zero_kernel wipes all probe garbage before the real run.
    int* dummy_rot = (int*)d_ws;
    unsigned long long* dummy_feat = (unsigned long long*)d_ws;

    hipLaunchKernelGGL(main_t<1>, dim3(FEAT_BLOCKS + ROT_BLOCKS), dim3(512), 0,
                       stream, pcd, dummy_rot, dummy_feat);   // probe: no trans
    hipLaunchKernelGGL(main_t<2>, dim3(FEAT_BLOCKS + ROT_BLOCKS), dim3(512), 0,
                       stream, pcd, dummy_rot, dummy_feat);   // probe: no 64-bit accum
    hipLaunchKernelGGL(zero_kernel, dim3((WS_ULL_TOTAL + 255) / 256), dim3(256), 0,
                       stream, (unsigned long long*)d_ws);
    hipLaunchKernelGGL(main_t<0>, dim3(FEAT_BLOCKS + ROT_BLOCKS), dim3(512), 0,
                       stream, pcd, rot_hist, feat_hist);     // real
    hipLaunchKernelGGL(write_kernel, dim3((BATCH * LVOX * 16 + 255) / 256), dim3(256),
                       0, stream, rot_hist, (const unsigned*)feat_hist, out);
}

// Round 12
// 37.230 us; speedup vs baseline: 2.2926x; 2.2926x over previous
//
#include <hip/hip_runtime.h>

#define BATCH  8
#define NPTS   16384
#define LVOX   605     // 11*11*5 = 121 xy-columns * 5 z
#define ABINS  8
#define CH     23
#define NCOL   121
#define NBIN   14      // floor(d) <= 13 (max dist 13.89); feature[14] == 1.0
#define BPTS   256     // points per feature block
#define FEAT_BLOCKS (BATCH * (NPTS / BPTS))   // 512
#define ROT_CH    4
#define ROT_CHPTS (NPTS / ROT_CH)             // 4096
#define ROT_BLOCKS (ABINS * BATCH * ROT_CH)   // 256

#define ROT_WS_U32  (ABINS * BATCH * LVOX)          // 38720
#define FEAT_WS_U32 (BATCH * LVOX * (NBIN / 2))     // 8*605*7 = 33880 (u16 pairs)
#define WS_U32_TOTAL (ROT_WS_U32 + FEAT_WS_U32)     // 72600  (~290 KB)

// ---------------------------------------------------------------------------
// Workspace zeroing — own kernel, no hipMemsetAsync.
// ---------------------------------------------------------------------------
__global__ __launch_bounds__(256) void zero_kernel(unsigned* __restrict__ ws) {
    const int i = blockIdx.x * 256 + threadIdx.x;
    if (i < WS_U32_TOTAL) ws[i] = 0u;
}

// ---------------------------------------------------------------------------
// Fused kernel, 512 threads.
// R12: replace register nibble-packing (64-bit VCC-serialized adds + LDS
// staging reduce) with a per-block LDS histogram hist[z][k][column] updated
// by ds_add_u32.  Lane=column => addresses are lane-consecutive => the free
// 2-way bank case; LDS-atomic issue runs parallel to VALU.  Inner loop per
// point-z: sub+fma+sqrt+cvt+addr+ds_add, no carries.
// Blocks [0,512): features (b, 256-pt chunk).  Waves: li=tid&127 = column,
// tid>>7 = point quarter.  Blocks [512,768): rot histogram (unchanged).
// ---------------------------------------------------------------------------
__global__ __launch_bounds__(512) void main_kernel(const float* __restrict__ pcd,
                                                   int* __restrict__ rot_hist,
                                                   unsigned* __restrict__ feat_hist) {
    __shared__ unsigned hist[5][NBIN][128];   // 35840 B
    __shared__ float4  pts[BPTS];             // 4096 B
    const int bid = blockIdx.x;
    const int tid = threadIdx.x;

    if (bid < FEAT_BLOCKS) {
        const int b     = bid >> 6;      // /64
        const int outer = bid & 63;

        // ---- stage 256 points into LDS (padded float4) + zero hist ----
        {
            const float* __restrict__ src = pcd + ((size_t)b * NPTS + outer * BPTS) * 3;
            float* pf = (float*)pts;
            for (int i = tid; i < BPTS * 3; i += 512) pf[(i / 3) * 4 + (i % 3)] = src[i];
            unsigned* hp = &hist[0][0][0];
            for (int i = tid; i < 5 * NBIN * 128; i += 512) hp[i] = 0u;
        }
        __syncthreads();

        const int li = tid & 127;                    // histogram column (0..127)
        const int cc = (li < NCOL) ? li : (NCOL - 1); // clamp math so k<=13
        const float lx = -5.0f + (float)(cc / 11);
        const float ly = -5.0f + (float)(cc % 11);
        const int pbase = (tid >> 7) * 64;           // wave-pair point quarter

#pragma unroll 4
        for (int j = 0; j < 64; ++j) {
            const float4 P = pts[pbase + j];
            const float dx = P.x - lx, dy = P.y - ly;
            const float rxy2 = fmaf(dy, dy, dx * dx);
            const float dz0 = P.z + 2.0f;
#pragma unroll
            for (int z = 0; z < 5; ++z) {
                const float dz = dz0 - (float)z;
                const float d  = __builtin_amdgcn_sqrtf(fmaf(dz, dz, rxy2));
                const int   k  = (int)d;             // floor(d) == ceil(d)-1 a.e.
                atomicAdd(&hist[z][k][li], 1u);      // ds_add_u32, conflict-free
            }
        }
        __syncthreads();

        // ---- epilogue: pack bin pairs (u16|u16), one global atomic each ----
        for (int item = tid; item < NCOL * 5 * (NBIN / 2); item += 512) {
            const int kp  = item % 7;
            const int rem = item / 7;
            const int z   = rem % 5;
            const int col = rem / 5;
            const unsigned v = hist[z][2 * kp][col] | (hist[z][2 * kp + 1][col] << 16);
            if (v) atomicAdd(&feat_hist[((size_t)b * LVOX + col * 5 + z) * 7 + kp], v);
        }
    } else {
        // ------------------ rotation-voxel histogram ------------------
        const int rb    = bid - FEAT_BLOCKS;
        const int ab    = rb & 63;        // a*8 + b
        const int chunk = rb >> 6;        // 0..3
        const int a     = ab >> 3;
        const int b     = ab & 7;

        int* h = (int*)&hist[0][0][0];
        for (int i = tid; i < LVOX; i += 512) h[i] = 0;
        __syncthreads();

        const float C[8] = { -4.3711388e-08f, 0.3826834323650898f, 0.7071067811865476f,
                             0.9238795325112867f, 1.0f, 0.9238795325112867f,
                             0.7071067811865476f, 0.3826834323650898f };
        const float S[8] = { -1.0f, -0.9238795325112867f, -0.7071067811865476f,
                             -0.3826834323650898f, 0.0f, 0.3826834323650898f,
                             0.7071067811865476f, 0.9238795325112867f };
        const float c = C[a];
        const float s = S[a];

        const float* __restrict__ p =
            pcd + ((size_t)b * NPTS + (size_t)chunk * ROT_CHPTS) * 3;

        for (int n = tid; n < ROT_CHPTS; n += 512) {
            const float x = p[n * 3 + 0];
            const float y = p[n * 3 + 1];
            const float z = p[n * 3 + 2];
            const float rx = x * c - y * s + 5.5f;
            const float ry = x * s + y * c + 5.5f;
            const float rz = z + 2.5f;
            const int icx = (int)floorf(rx);
            const int icy = (int)floorf(ry);
            const int icz = (int)floorf(rz);
            const int flat = icz + icy * 5 + icx * 55;
            if (flat >= 0 && flat < LVOX) atomicAdd(&h[flat], 1);
        }
        __syncthreads();

        int* __restrict__ dst = rot_hist + (size_t)ab * LVOX;
        for (int i = tid; i < LVOX; i += 512) {
            const int v = h[i];
            if (v) atomicAdd(&dst[i], v);
        }
    }
}

// ---------------------------------------------------------------------------
// Finalize.  16-lane groups per (b,l): lane q<14 loads its u16 bin count,
// inclusive prefix-scan -> cumulative feature; feature[14] == 1.0 exactly.
// Lanes 0..7 also write the 8 rot channels.
// ---------------------------------------------------------------------------
__global__ __launch_bounds__(256) void write_kernel(const int* __restrict__ rot_hist,
                                                    const unsigned* __restrict__ feat16,
                                                    float* __restrict__ out) {
    const int gt    = blockIdx.x * 256 + threadIdx.x;
    const int group = gt >> 4;                 // (b,l)
    const int q     = gt & 15;
    if (group >= BATCH * LVOX) return;
    const int b = group / LVOX;
    const int l = group % LVOX;

    int v = 0;
    if (q < NBIN) {
        const unsigned w = feat16[(size_t)group * 7 + (q >> 1)];
        v = (int)((w >> (16 * (q & 1))) & 0xFFFFu);
    }
#pragma unroll
    for (int off = 1; off < 16; off <<= 1) {
        const int t = __shfl_up(v, off, 16);
        if (q >= off) v += t;
    }
    const float inv_n = 1.0f / (float)NPTS;
    float* __restrict__ o = out + (size_t)group * CH;
    if (q < NBIN)       o[q]  = (float)v * inv_n;
    else if (q == NBIN) o[14] = 1.0f;
    if (q < 8) {
        const int r = rot_hist[((size_t)q * BATCH + b) * LVOX + l];
        o[15 + q] = (float)r * inv_n;
    }
}

extern "C" void kernel_launch(void* const* d_in, const int* in_sizes, int n_in,
                              void* d_out, int out_size, void* d_ws, size_t ws_size,
                              hipStream_t stream) {
    const float* pcd = (const float*)d_in[0];
    float* out = (float*)d_out;
    int* rot_hist = (int*)d_ws;
    unsigned* feat16 = (unsigned*)d_ws + ROT_WS_U32;

    hipLaunchKernelGGL(zero_kernel, dim3((WS_U32_TOTAL + 255) / 256), dim3(256), 0,
                       stream, (unsigned*)d_ws);
    hipLaunchKernelGGL(main_kernel, dim3(FEAT_BLOCKS + ROT_BLOCKS), dim3(512), 0,
                       stream, pcd, rot_hist, feat16);
    hipLaunchKernelGGL(write_kernel, dim3((BATCH * LVOX * 16 + 255) / 256), dim3(256),
                       0, stream, rot_hist, feat16, out);
}